// Round 5
// baseline (17107.664 us; speedup 1.0000x reference)
//
#include <hip/hip_runtime.h>

#define S_LEN 1024
#define BATCH 64
#define HIDDEN 512
#define NBLK 32            // merged: each block owns 16 cols of BOTH layers
#define COLS_PER_BLK 16

typedef __attribute__((ext_vector_type(8))) short short8;   // 8 bf16 (4 VGPRs) MFMA frag
typedef __attribute__((ext_vector_type(4))) float f32x4;    // MFMA accumulator
typedef __attribute__((ext_vector_type(4))) unsigned int u32x4;

__device__ __forceinline__ unsigned short f2bf(float x) {
  unsigned u = __builtin_bit_cast(unsigned, x);
  u += 0x7fffu + ((u >> 16) & 1u);          // round-to-nearest-even
  return (unsigned short)(u >> 16);
}
__device__ __forceinline__ float bf2f(unsigned short h) {
  unsigned u = ((unsigned)h) << 16;
  return __builtin_bit_cast(float, u);
}

// device-scope write-through 16B store (lands at coherence point; no dirty L2 line)
__device__ __forceinline__ void st16_sc1(void* p, u32x4 v) {
  asm volatile("global_store_dwordx4 %0, %1, off sc1" :: "v"(p), "v"(v) : "memory");
}

// fragment load: two relaxed agent (sc1) 8B atomic loads -> 16B MFMA A-fragment.
__device__ __forceinline__ short8 ld_frag(const unsigned long long* p) {
  union { unsigned long long q[2]; short8 s; } u;
  u.q[0] = __hip_atomic_load(p,     __ATOMIC_RELAXED, __HIP_MEMORY_SCOPE_AGENT);
  u.q[1] = __hip_atomic_load(p + 1, __ATOMIC_RELAXED, __HIP_MEMORY_SCOPE_AGENT);
  return u.s;
}

// h state layout: MFMA-A-fragment packed, [parity][wid][kc][lane][8] bf16 shorts.
#define HOFF(p, w, kc, l) ((((((p) * 4 + (w)) * 16 + (kc)) * 64 + (l))) * 8)

// ws layout: [0,2KB) arrival flags (one per block, stride 16 uints = own 64B line);
// [4KB,6KB) epoch mailboxes (one per block, stride 16 uints);
// [8KB,...) 4 packed h buffers (h0_hi, h0_lo, h1_hi, h1_lo), each 65536 shorts = 128KB.
__global__ void k_init(unsigned* __restrict__ ws, int* __restrict__ hbufs) {
  int i = blockIdx.x * blockDim.x + threadIdx.x;
  if (i < 2048) ws[i] = 0u;                 // flags + mail (8KB)
  for (int k = i; k < 131072; k += gridDim.x * blockDim.x) hbufs[k] = 0;
}

__launch_bounds__(256, 1)
__global__ void k_rnn(const int* __restrict__ x, const float* __restrict__ emb,
                      const float* __restrict__ Wih0, const float* __restrict__ b0,
                      const float* __restrict__ Whh0, const float* __restrict__ Wih1,
                      const float* __restrict__ b1, const float* __restrict__ Whh1,
                      float* __restrict__ out, unsigned* __restrict__ flags,
                      short* __restrict__ hbase) {
  // LDS: 8 W-fragment regions: {wih0,whh0,wih1,whh1} x {hi,lo}, each [16 kc][64 lanes][8]
  __shared__ short wlds[8 * 16 * 64 * 8];                 // 128 KB
  __shared__ __align__(16) short stage0[2][4][32][8];     // 4 KB (h0 publish)
  __shared__ __align__(16) short stage1[2][4][32][8];     // 4 KB (h1 publish)

  const int tid  = threadIdx.x;
  const int wid  = tid >> 6;
  const int lane = tid & 63;
  const int bx   = blockIdx.x;
  const int col0 = bx * COLS_PER_BLK;

  unsigned* mail = flags + 1024;             // [4KB,6KB) region

  // ---- stage W column-slices into LDS as pre-packed MFMA B-fragments (hi/lo bf16) ----
  {
    const float* Wm[4] = {Wih0, Whh0, Wih1, Whh1};
    const int c = col0 + (lane & 15);
    #pragma unroll
    for (int m = 0; m < 4; ++m) {
      const float* W = Wm[m];
      for (int kc = wid; kc < 16; kc += 4) {
        const int k0 = kc * 32 + (lane >> 4) * 8;
        const int basei = (kc * 64 + lane) * 8;
        #pragma unroll
        for (int j = 0; j < 8; ++j) {
          float v = W[(size_t)(k0 + j) * HIDDEN + c];
          unsigned short vh = f2bf(v);
          wlds[(m * 2    ) * 8192 + basei + j] = (short)vh;
          wlds[(m * 2 + 1) * 8192 + basei + j] = (short)f2bf(v - bf2f(vh));
        }
      }
    }
  }
  __syncthreads();

  short* h0_hi = hbase;                       // packed, 65536 shorts each
  short* h0_lo = hbase + 65536;
  short* h1_hi = hbase + 131072;
  short* h1_lo = hbase + 196608;
  const unsigned long long* h0_hi64 = (const unsigned long long*)h0_hi;
  const unsigned long long* h0_lo64 = (const unsigned long long*)h0_lo;
  const unsigned long long* h1_hi64 = (const unsigned long long*)h1_hi;
  const unsigned long long* h1_lo64 = (const unsigned long long*)h1_lo;

  const int arow  = wid * 16 + (lane & 15);   // A-fragment row = batch index
  const int kgo   = (lane >> 4) * 8;          // k offset inside a 32-chunk
  const int ccol  = col0 + (lane & 15);       // D col (m89-verified C/D map)
  const int drow0 = wid * 16 + (lane >> 4) * 4; // D row base
  const float bc0 = b0[ccol];
  const float bc1 = b1[ccol];

  // publication coords: block's 16 cols live in half of one 32-k-chunk
  const int skc   = col0 >> 5;
  const int sub0  = (bx & 1) * 2;
  const int slotb = (lane >> 4) * 4 + 16 * ((lane & 15) >> 3);  // + j = local slot
  const int sjj   = lane & 7;

  float* out_seq = out;                                  // [64][1024][512]
  float* hidden  = out + (size_t)BATCH * S_LEN * HIDDEN; // [2][64][512]

  short8 ea_reg[16];
  #define LOAD_EA(t) do {                                                   \
    const int xr_ = x[arow * S_LEN + (t)];                                  \
    const float* erow_ = emb + (size_t)xr_ * HIDDEN;                        \
    _Pragma("unroll")                                                       \
    for (int kc = 0; kc < 16; ++kc) {                                       \
      const float4* ep_ = (const float4*)(erow_ + kc * 32 + kgo);           \
      float4 e0_ = ep_[0], e1_ = ep_[1];                                    \
      short8 ea_;                                                           \
      ea_[0] = (short)f2bf(e0_.x); ea_[1] = (short)f2bf(e0_.y);             \
      ea_[2] = (short)f2bf(e0_.z); ea_[3] = (short)f2bf(e0_.w);             \
      ea_[4] = (short)f2bf(e1_.x); ea_[5] = (short)f2bf(e1_.y);             \
      ea_[6] = (short)f2bf(e1_.z); ea_[7] = (short)f2bf(e1_.w);             \
      ea_reg[kc] = ea_;                                                     \
    } } while (0)

  LOAD_EA(0);

  for (int i = 0; i <= S_LEN; ++i) {
    const int p = i & 1;                     // h0_t stored at parity t&1; h1_t at t&1
    const int q = p ^ 1;
    const bool doL0 = (i < S_LEN);
    const bool doL1 = (i >= 1);

    // ---- fused compute: h0_i = tanh(ea@Wih0 + b0 + h0_{i-1}@Whh0)
    //                     h1_{i-1} = tanh(h0_{i-1}@Wih1 + b1 + h1_{i-2}@Whh1)
    // h0_{i-1} fragments (ah/al) are loaded ONCE and feed both layers' MFMAs.
    f32x4 aA0 = {bc0, bc0, bc0, bc0};
    f32x4 aA1 = {0.f, 0.f, 0.f, 0.f};
    f32x4 aB0 = {bc1, bc1, bc1, bc1};
    f32x4 aB1 = {0.f, 0.f, 0.f, 0.f};
    #pragma unroll
    for (int kc = 0; kc < 16; ++kc) {
      const int o0 = HOFF(q, wid, kc, lane) >> 2;        // h0_{i-1}
      short8 ah = ld_frag(h0_hi64 + o0);
      short8 al = ld_frag(h0_lo64 + o0);
      const int fb = (kc * 64 + lane) * 8;
      if (doL0) {
        short8 w0h = *(const short8*)&wlds[0 * 8192 + fb];
        short8 w0l = *(const short8*)&wlds[1 * 8192 + fb];
        short8 g0h = *(const short8*)&wlds[2 * 8192 + fb];
        short8 g0l = *(const short8*)&wlds[3 * 8192 + fb];
        f32x4& ac = (kc & 1) ? aA1 : aA0;
        ac = __builtin_amdgcn_mfma_f32_16x16x32_bf16(ea_reg[kc], w0h, ac, 0, 0, 0);
        ac = __builtin_amdgcn_mfma_f32_16x16x32_bf16(ea_reg[kc], w0l, ac, 0, 0, 0);
        ac = __builtin_amdgcn_mfma_f32_16x16x32_bf16(ah, g0h, ac, 0, 0, 0);
        ac = __builtin_amdgcn_mfma_f32_16x16x32_bf16(ah, g0l, ac, 0, 0, 0);
        ac = __builtin_amdgcn_mfma_f32_16x16x32_bf16(al, g0h, ac, 0, 0, 0);
      }
      if (doL1) {
        const int o1 = HOFF(p, wid, kc, lane) >> 2;      // h1_{i-2}
        short8 ch = ld_frag(h1_hi64 + o1);
        short8 cl = ld_frag(h1_lo64 + o1);
        short8 w1h = *(const short8*)&wlds[4 * 8192 + fb];
        short8 w1l = *(const short8*)&wlds[5 * 8192 + fb];
        short8 g1h = *(const short8*)&wlds[6 * 8192 + fb];
        short8 g1l = *(const short8*)&wlds[7 * 8192 + fb];
        f32x4& bcx = (kc & 1) ? aB1 : aB0;
        bcx = __builtin_amdgcn_mfma_f32_16x16x32_bf16(ah, w1h, bcx, 0, 0, 0);
        bcx = __builtin_amdgcn_mfma_f32_16x16x32_bf16(ah, w1l, bcx, 0, 0, 0);
        bcx = __builtin_amdgcn_mfma_f32_16x16x32_bf16(al, w1h, bcx, 0, 0, 0);
        bcx = __builtin_amdgcn_mfma_f32_16x16x32_bf16(ch, g1h, bcx, 0, 0, 0);
        bcx = __builtin_amdgcn_mfma_f32_16x16x32_bf16(ch, g1l, bcx, 0, 0, 0);
        bcx = __builtin_amdgcn_mfma_f32_16x16x32_bf16(cl, g1h, bcx, 0, 0, 0);
      }
    }

    if (doL0) {        // publish h0_i @ parity p
      #pragma unroll
      for (int j = 0; j < 4; ++j) {
        float hv = tanhf(aA0[j] + aA1[j]);
        unsigned short hi = f2bf(hv);
        unsigned short lo = f2bf(hv - bf2f(hi));
        stage0[0][wid][slotb + j][sjj] = (short)hi;
        stage0[1][wid][slotb + j][sjj] = (short)lo;
        if (i == S_LEN - 1) hidden[(drow0 + j) * HIDDEN + ccol] = hv;  // hidden[0]
      }
      asm volatile("s_waitcnt lgkmcnt(0)" ::: "memory");
      const int l2 = lane & 31, sel = lane >> 5;
      u32x4 v = *(const u32x4*)&stage0[sel][wid][l2][0];
      short* dst = (sel ? h0_lo : h0_hi) +
                   (((p * 4 + wid) * 16 + skc) * 64 + sub0 * 16 + l2) * 8;
      st16_sc1(dst, v);
    }
    if (doL1) {        // publish h1_{i-1} @ parity q, plus outputs
      const int t = i - 1;
      #pragma unroll
      for (int j = 0; j < 4; ++j) {
        const int r = drow0 + j;
        float hv = tanhf(aB0[j] + aB1[j]);
        unsigned short hi = f2bf(hv);
        unsigned short lo = f2bf(hv - bf2f(hi));
        stage1[0][wid][slotb + j][sjj] = (short)hi;
        stage1[1][wid][slotb + j][sjj] = (short)lo;
        out_seq[(size_t)r * S_LEN * HIDDEN + (size_t)t * HIDDEN + ccol] = hv;
        if (i == S_LEN) hidden[32768 + r * HIDDEN + ccol] = hv;        // hidden[1]
      }
      asm volatile("s_waitcnt lgkmcnt(0)" ::: "memory");
      const int l2 = lane & 31, sel = lane >> 5;
      u32x4 v = *(const u32x4*)&stage1[sel][wid][l2][0];
      short* dst = (sel ? h1_lo : h1_hi) +
                   (((q * 4 + wid) * 16 + skc) * 64 + sub0 * 16 + l2) * 8;
      st16_sc1(dst, v);
    }

    // ---- device-scope barrier i: single-reader lines only ----
    // arrival flag: 1 writer (this block) / 1 reader (master).
    // mailbox:      1 writer (master)     / readers = this block's waves (same addr).
    if (i < S_LEN) {
      asm volatile("s_waitcnt vmcnt(0)" ::: "memory");  // sc1 publishes + out stores drained
      __syncthreads();                                  // all 4 waves' work complete
      if (tid == 0)
        __hip_atomic_store(&flags[bx * 16], (unsigned)(i + 1),
                           __ATOMIC_RELAXED, __HIP_MEMORY_SCOPE_AGENT);
      if (i + 1 < S_LEN) LOAD_EA(i + 1);   // overlap emb prefetch with barrier wait
      __builtin_amdgcn_sched_barrier(0);   // pin prefetch issue before the poll loop
      if (bx == 0 && wid == 0) {
        // master: poll 32 per-block flags (one lane per flag line)
        for (;;) {
          unsigned f = __hip_atomic_load(&flags[(lane & 31) * 16],
                                         __ATOMIC_RELAXED, __HIP_MEMORY_SCOPE_AGENT);
          if (__all((int)(f > (unsigned)i))) break;
          __builtin_amdgcn_s_sleep(1);
        }
        if (lane < 32)                      // broadcast epoch to per-block mailboxes
          __hip_atomic_store(&mail[lane * 16], (unsigned)(i + 1),
                             __ATOMIC_RELAXED, __HIP_MEMORY_SCOPE_AGENT);
      } else {
        // workers: poll own mailbox only (all lanes same addr -> one request/poll)
        for (;;) {
          unsigned m = __hip_atomic_load(&mail[bx * 16],
                                         __ATOMIC_RELAXED, __HIP_MEMORY_SCOPE_AGENT);
          if (m > (unsigned)i) break;
          __builtin_amdgcn_s_sleep(1);
        }
      }
      asm volatile("" ::: "memory");        // no hoisting past the spin
    }
  }
  #undef LOAD_EA
}

extern "C" void kernel_launch(void* const* d_in, const int* in_sizes, int n_in,
                              void* d_out, int out_size, void* d_ws, size_t ws_size,
                              hipStream_t stream) {
  const int*   x    = (const int*)d_in[0];
  // d_in[1] = lengths : unused by the reference
  const float* emb  = (const float*)d_in[2];
  const float* Wih0 = (const float*)d_in[3];
  const float* b0   = (const float*)d_in[4];
  const float* Whh0 = (const float*)d_in[5];
  const float* Wih1 = (const float*)d_in[6];
  const float* b1   = (const float*)d_in[7];
  const float* Whh1 = (const float*)d_in[8];
  float* out = (float*)d_out;

  unsigned* flags = (unsigned*)d_ws;
  short*    hbase = (short*)((char*)d_ws + 8192);

  // re-zero flags/mail + initial h-state every call (ws not re-poisoned between
  // replays; k_init's kernel-boundary flush makes zeros visible at the CP)
  k_init<<<256, 256, 0, stream>>>(flags, (int*)hbase);
  k_rnn<<<NBLK, 256, 0, stream>>>(x, emb, Wih0, b0, Whh0, Wih1, b1, Whh1, out, flags, hbase);
}

// Round 7
// 11698.852 us; speedup vs baseline: 1.4623x; 1.4623x over previous
//
#include <hip/hip_runtime.h>

#define S_LEN 1024
#define BATCH 64
#define HIDDEN 512
#define NBLK 32            // 32 workers = all CUs of ONE XCD; each owns 16 cols of BOTH layers
#define COLS_PER_BLK 16
#define GRID_CAND 1024     // candidate blocks for XCD-pinning
#define FALLBACK_ITERS 64  // local-flag polls before also watching the proven CP channel

typedef __attribute__((ext_vector_type(8))) short short8;   // 8 bf16 (4 VGPRs) MFMA frag
typedef __attribute__((ext_vector_type(4))) float f32x4;    // MFMA accumulator
typedef __attribute__((ext_vector_type(4))) unsigned int u32x4;

__device__ __forceinline__ unsigned short f2bf(float x) {
  unsigned u = __builtin_bit_cast(unsigned, x);
  u += 0x7fffu + ((u >> 16) & 1u);          // round-to-nearest-even
  return (unsigned short)(u >> 16);
}
__device__ __forceinline__ float bf2f(unsigned short h) {
  unsigned u = ((unsigned)h) << 16;
  return __builtin_bit_cast(float, u);
}

// h state layout: MFMA-A-fragment packed, [parity][wid][kc][lane][8] bf16 shorts.
#define HOFF(p, w, kc, l) ((((((p) * 4 + (w)) * 16 + (kc)) * 64 + (l))) * 8)

// ws layout (uint idx): [0,512) CP atomic flags (32 slots x 16 uints);
// [512] ticket; [576,1088) local plain flags (32 slots x 16 uints);
// byte 16384+: 4 packed h buffers (h0_hi,h0_lo,h1_hi,h1_lo), 65536 shorts each.
__global__ void k_init(unsigned* __restrict__ ws, int* __restrict__ hbufs) {
  int i = blockIdx.x * blockDim.x + threadIdx.x;
  if (i < 2048) ws[i] = 0u;
  for (int k = i; k < 131072; k += gridDim.x * blockDim.x) hbufs[k] = 0;
}

// take an XCD-0 worker slot (or -1): only blocks physically on XCD 0 participate,
// so all workers share one L2. Non-workers exit and free their CU.
__device__ __forceinline__ int take_slot(unsigned* ticket, int* slot_sh) {
  if (threadIdx.x == 0) {
    unsigned xcc;
    asm volatile("s_getreg_b32 %0, hwreg(HW_REG_XCC_ID)" : "=s"(xcc));
    int s = -1;
    if (xcc == 0)
      s = (int)__hip_atomic_fetch_add(ticket, 1u, __ATOMIC_RELAXED,
                                      __HIP_MEMORY_SCOPE_AGENT);
    *slot_sh = s;
  }
  __syncthreads();
  return *slot_sh;
}

__launch_bounds__(256, 1)
__global__ void k_rnn(const int* __restrict__ x, const float* __restrict__ emb,
                      const float* __restrict__ Wih0, const float* __restrict__ b0,
                      const float* __restrict__ Whh0, const float* __restrict__ Wih1,
                      const float* __restrict__ b1, const float* __restrict__ Whh1,
                      float* __restrict__ out, unsigned* __restrict__ ws_u,
                      short* __restrict__ hbase) {
  __shared__ short wlds[8 * 16 * 64 * 8];                 // 128 KB weight fragments
  __shared__ __align__(16) short stage0[2][4][32][8];     // 4 KB (h0 publish)
  __shared__ __align__(16) short stage1[2][4][32][8];     // 4 KB (h1 publish)
  __shared__ int slot_sh;

  unsigned* cpflag = ws_u;                  // proven CP atomic channel
  unsigned* lflag  = ws_u + 576;            // XCD-local plain channel

  const int slot = take_slot(ws_u + 512, &slot_sh);
  if ((unsigned)slot >= NBLK) return;       // not an XCD-0 worker

  const int tid  = threadIdx.x;
  const int wid  = tid >> 6;
  const int lane = tid & 63;
  const int col0 = slot * COLS_PER_BLK;

  // ---- stage W column-slices into LDS as pre-packed MFMA B-fragments (hi/lo bf16) ----
  {
    const float* Wm[4] = {Wih0, Whh0, Wih1, Whh1};
    const int c = col0 + (lane & 15);
    #pragma unroll
    for (int m = 0; m < 4; ++m) {
      const float* W = Wm[m];
      for (int kc = wid; kc < 16; kc += 4) {
        const int k0 = kc * 32 + (lane >> 4) * 8;
        const int basei = (kc * 64 + lane) * 8;
        #pragma unroll
        for (int j = 0; j < 8; ++j) {
          float v = W[(size_t)(k0 + j) * HIDDEN + c];
          unsigned short vh = f2bf(v);
          wlds[(m * 2    ) * 8192 + basei + j] = (short)vh;
          wlds[(m * 2 + 1) * 8192 + basei + j] = (short)f2bf(v - bf2f(vh));
        }
      }
    }
  }
  __syncthreads();

  short* h0_hi = hbase;                       // packed, 65536 shorts each
  short* h0_lo = hbase + 65536;
  short* h1_hi = hbase + 131072;
  short* h1_lo = hbase + 196608;

  const int arow  = wid * 16 + (lane & 15);   // A-fragment row = batch index
  const int kgo   = (lane >> 4) * 8;          // k offset inside a 32-chunk
  const int ccol  = col0 + (lane & 15);       // D col (m89-verified C/D map)
  const int drow0 = wid * 16 + (lane >> 4) * 4; // D row base
  const float bc0 = b0[ccol];
  const float bc1 = b1[ccol];

  // publication coords: block's 16 cols live in half of one 32-k-chunk
  const int skc   = col0 >> 5;
  const int sub0  = (slot & 1) * 2;
  const int slotb = (lane >> 4) * 4 + 16 * ((lane & 15) >> 3);  // + j = local slot
  const int sjj   = lane & 7;

  float* out_seq = out;                                  // [64][1024][512]
  float* hidden  = out + (size_t)BATCH * S_LEN * HIDDEN; // [2][64][512]

  unsigned*       mylocal = lflag  + slot * 16;
  unsigned*       mycp    = cpflag + slot * 16;
  const unsigned* lp      = lflag  + (lane & 31) * 16;   // lane l watches slot l&31
  const unsigned* cp      = cpflag + (lane & 31) * 16;

  short8 ea_reg[16];
  #define LOAD_EA(t) do {                                                   \
    const int xr_ = x[arow * S_LEN + (t)];                                  \
    const float* erow_ = emb + (size_t)xr_ * HIDDEN;                        \
    _Pragma("unroll")                                                       \
    for (int kc = 0; kc < 16; ++kc) {                                       \
      const float4* ep_ = (const float4*)(erow_ + kc * 32 + kgo);           \
      float4 e0_ = ep_[0], e1_ = ep_[1];                                    \
      short8 ea_;                                                           \
      ea_[0] = (short)f2bf(e0_.x); ea_[1] = (short)f2bf(e0_.y);             \
      ea_[2] = (short)f2bf(e0_.z); ea_[3] = (short)f2bf(e0_.w);             \
      ea_[4] = (short)f2bf(e1_.x); ea_[5] = (short)f2bf(e1_.y);             \
      ea_[6] = (short)f2bf(e1_.z); ea_[7] = (short)f2bf(e1_.w);             \
      ea_reg[kc] = ea_;                                                     \
    } } while (0)

  LOAD_EA(0);

  for (int i = 0; i <= S_LEN; ++i) {
    const int p = i & 1;
    const int q = p ^ 1;
    const bool doL0 = (i < S_LEN);
    const bool doL1 = (i >= 1);

    // ---- fused compute: h0_i = tanh(ea@Wih0 + b0 + h0_{i-1}@Whh0)
    //                     h1_{i-1} = tanh(h0_{i-1}@Wih1 + b1 + h1_{i-2}@Whh1)
    // Plain loads from the shared XCD-0 L2 (vL1 invalidated at barrier exit).
    f32x4 aA0 = {bc0, bc0, bc0, bc0};
    f32x4 aA1 = {0.f, 0.f, 0.f, 0.f};
    f32x4 aB0 = {bc1, bc1, bc1, bc1};
    f32x4 aB1 = {0.f, 0.f, 0.f, 0.f};
    #pragma unroll
    for (int kc = 0; kc < 16; ++kc) {
      const int o0 = HOFF(q, wid, kc, lane);             // h0_{i-1}
      short8 ah = *(const short8*)(h0_hi + o0);
      short8 al = *(const short8*)(h0_lo + o0);
      const int fb = (kc * 64 + lane) * 8;
      if (doL0) {
        short8 w0h = *(const short8*)&wlds[0 * 8192 + fb];
        short8 w0l = *(const short8*)&wlds[1 * 8192 + fb];
        short8 g0h = *(const short8*)&wlds[2 * 8192 + fb];
        short8 g0l = *(const short8*)&wlds[3 * 8192 + fb];
        f32x4& ac = (kc & 1) ? aA1 : aA0;
        ac = __builtin_amdgcn_mfma_f32_16x16x32_bf16(ea_reg[kc], w0h, ac, 0, 0, 0);
        ac = __builtin_amdgcn_mfma_f32_16x16x32_bf16(ea_reg[kc], w0l, ac, 0, 0, 0);
        ac = __builtin_amdgcn_mfma_f32_16x16x32_bf16(ah, g0h, ac, 0, 0, 0);
        ac = __builtin_amdgcn_mfma_f32_16x16x32_bf16(ah, g0l, ac, 0, 0, 0);
        ac = __builtin_amdgcn_mfma_f32_16x16x32_bf16(al, g0h, ac, 0, 0, 0);
      }
      if (doL1) {
        const int o1 = HOFF(p, wid, kc, lane);           // h1_{i-2}
        short8 ch = *(const short8*)(h1_hi + o1);
        short8 cl = *(const short8*)(h1_lo + o1);
        short8 w1h = *(const short8*)&wlds[4 * 8192 + fb];
        short8 w1l = *(const short8*)&wlds[5 * 8192 + fb];
        short8 g1h = *(const short8*)&wlds[6 * 8192 + fb];
        short8 g1l = *(const short8*)&wlds[7 * 8192 + fb];
        f32x4& bcx = (kc & 1) ? aB1 : aB0;
        bcx = __builtin_amdgcn_mfma_f32_16x16x32_bf16(ah, w1h, bcx, 0, 0, 0);
        bcx = __builtin_amdgcn_mfma_f32_16x16x32_bf16(ah, w1l, bcx, 0, 0, 0);
        bcx = __builtin_amdgcn_mfma_f32_16x16x32_bf16(al, w1h, bcx, 0, 0, 0);
        bcx = __builtin_amdgcn_mfma_f32_16x16x32_bf16(ch, g1h, bcx, 0, 0, 0);
        bcx = __builtin_amdgcn_mfma_f32_16x16x32_bf16(ch, g1l, bcx, 0, 0, 0);
        bcx = __builtin_amdgcn_mfma_f32_16x16x32_bf16(cl, g1h, bcx, 0, 0, 0);
      }
    }

    if (doL0) {        // publish h0_i @ parity p (plain write-through -> local L2)
      #pragma unroll
      for (int j = 0; j < 4; ++j) {
        float hv = tanhf(aA0[j] + aA1[j]);
        unsigned short hi = f2bf(hv);
        unsigned short lo = f2bf(hv - bf2f(hi));
        stage0[0][wid][slotb + j][sjj] = (short)hi;
        stage0[1][wid][slotb + j][sjj] = (short)lo;
        if (i == S_LEN - 1) hidden[(drow0 + j) * HIDDEN + ccol] = hv;  // hidden[0]
      }
      asm volatile("s_waitcnt lgkmcnt(0)" ::: "memory");
      const int l2 = lane & 31, sel = lane >> 5;
      u32x4 v = *(const u32x4*)&stage0[sel][wid][l2][0];
      short* dst = (sel ? h0_lo : h0_hi) +
                   (((p * 4 + wid) * 16 + skc) * 64 + sub0 * 16 + l2) * 8;
      *(u32x4*)dst = v;
    }
    if (doL1) {        // publish h1_{i-1} @ parity q, plus outputs
      const int t = i - 1;
      #pragma unroll
      for (int j = 0; j < 4; ++j) {
        const int r = drow0 + j;
        float hv = tanhf(aB0[j] + aB1[j]);
        unsigned short hi = f2bf(hv);
        unsigned short lo = f2bf(hv - bf2f(hi));
        stage1[0][wid][slotb + j][sjj] = (short)hi;
        stage1[1][wid][slotb + j][sjj] = (short)lo;
        out_seq[(size_t)r * S_LEN * HIDDEN + (size_t)t * HIDDEN + ccol] = hv;
        if (i == S_LEN) hidden[32768 + r * HIDDEN + ccol] = hv;        // hidden[1]
      }
      asm volatile("s_waitcnt lgkmcnt(0)" ::: "memory");
      const int l2 = lane & 31, sel = lane >> 5;
      u32x4 v = *(const u32x4*)&stage1[sel][wid][l2][0];
      short* dst = (sel ? h1_lo : h1_hi) +
                   (((q * 4 + wid) * 16 + skc) * 64 + sub0 * 16 + l2) * 8;
      *(u32x4*)dst = v;
    }

    // ---- XCD-local barrier i, dual-channel (hang-proof) ----
    // Arrival: vmcnt(0) drains publishes into L2 -> plain local flag + CP atomic flag.
    // Poll: fast path = buffer_inv + plain load (local L2); after FALLBACK_ITERS
    // also poll the PROVEN CP atomic channel -> progress guaranteed.
    if (i < S_LEN) {
      asm volatile("s_waitcnt vmcnt(0)" ::: "memory");  // publishes ACKed by L2
      __syncthreads();                                  // all 4 waves drained
      const unsigned e = (unsigned)(i + 1);
      if (tid == 0) {
        asm volatile("global_store_dword %0, %1, off" :: "v"(mylocal), "v"(e) : "memory");
        __hip_atomic_store(mycp, e, __ATOMIC_RELAXED, __HIP_MEMORY_SCOPE_AGENT);
      }
      if (i + 1 < S_LEN) LOAD_EA(i + 1);   // overlap emb prefetch with barrier wait
      __builtin_amdgcn_sched_barrier(0);
      int tries = 0;
      for (;;) {
        unsigned f;
        asm volatile("buffer_inv\n\t"
                     "global_load_dword %0, %1, off\n\t"
                     "s_waitcnt vmcnt(0)"
                     : "=v"(f) : "v"(lp) : "memory");
        if (tries >= FALLBACK_ITERS) {
          unsigned g = __hip_atomic_load(cp, __ATOMIC_RELAXED, __HIP_MEMORY_SCOPE_AGENT);
          if (g > f) f = g;
          __builtin_amdgcn_s_sleep(1);
        }
        if (__all((int)(f > (unsigned)i))) break;
        ++tries;
      }
      asm volatile("buffer_inv" ::: "memory");  // fresh vL1 for next step's h loads
    }
  }
  #undef LOAD_EA
}

extern "C" void kernel_launch(void* const* d_in, const int* in_sizes, int n_in,
                              void* d_out, int out_size, void* d_ws, size_t ws_size,
                              hipStream_t stream) {
  const int*   x    = (const int*)d_in[0];
  // d_in[1] = lengths : unused by the reference
  const float* emb  = (const float*)d_in[2];
  const float* Wih0 = (const float*)d_in[3];
  const float* b0   = (const float*)d_in[4];
  const float* Whh0 = (const float*)d_in[5];
  const float* Wih1 = (const float*)d_in[6];
  const float* b1   = (const float*)d_in[7];
  const float* Whh1 = (const float*)d_in[8];
  float* out = (float*)d_out;

  unsigned* ws_u  = (unsigned*)d_ws;
  short*    hbase = (short*)((char*)d_ws + 16384);

  // re-zero flags/ticket + initial h-state every call (ws not re-poisoned between
  // replays; kernel-boundary cache ops make zeros visible device-wide)
  k_init<<<256, 256, 0, stream>>>(ws_u, (int*)hbase);
  k_rnn<<<GRID_CAND, 256, 0, stream>>>(x, emb, Wih0, b0, Whh0, Wih1, b1, Whh1,
                                       out, ws_u, hbase);
}